// Round 11
// baseline (139.815 us; speedup 1.0000x reference)
//
#include <hip/hip_runtime.h>
#include <math.h>

#define NPTS 200
#define NCH  13
#define BLK  64
#define FPB  (NPTS * NCH)          // 2600 floats per batch
#define STG  5200                  // floats staged per wave (batches g=0,1)

// 4-byte-aligned float4 for dword-aligned (not 16B-aligned) vector loads
typedef float f4u __attribute__((ext_vector_type(4), aligned(4)));

// 12-byte packed store (align 4) for coalesced per-point output
typedef struct { float x, y, z; } f3s;

#define ACCUMULATE(Q0,Q1,Q2,Q3,Q4,Q5,Q6,Q7,Q8,Q9,Q10,Q11,Q12)               \
    {                                                                        \
        float wt = aa * (Q0) + bb;                                           \
        wt = fmaxf(wt, 0.f) + 1e-8f;                                         \
        const float v1x = fmaf(shift, (Q7),  (Q1));                          \
        const float v1y = fmaf(shift, (Q8),  (Q2));                          \
        const float v1z = fmaf(shift, (Q9),  (Q3));                          \
        const float v2x = fmaf(shift, (Q10), (Q4));                          \
        const float v2y = fmaf(shift, (Q11), (Q5));                          \
        const float v2z = fmaf(shift, (Q12), (Q6));                          \
        const float wv2x = wt * v2x, wv2y = wt * v2y, wv2z = wt * v2z;       \
        acc[0] += wt;                                                        \
        acc[1] += wt * v1x; acc[2] += wt * v1y; acc[3] += wt * v1z;          \
        acc[4] += wv2x;     acc[5] += wv2y;     acc[6] += wv2z;              \
        acc[7]  += wv2x * v1x; acc[8]  += wv2x * v1y; acc[9]  += wv2x * v1z; \
        acc[10] += wv2y * v1x; acc[11] += wv2y * v1y; acc[12] += wv2y * v1z; \
        acc[13] += wv2z * v1x; acc[14] += wv2z * v1y; acc[15] += wv2z * v1z; \
    }

// Branchless symmetric 4x4 Jacobi rotation on pair (P,Q) — HW-verified in
// v6/v7/v8 at absmax 0.015625. apq==0 => identity rotation; NaN killed by
// the select.
#define ROTB(dp, dq, opq, e1p, e1q, e2p, e2q, P, Q)                          \
    {                                                                        \
        const float apq = opq;                                               \
        const float tau = (dq - dp) * 0.5f * __builtin_amdgcn_rcpf(apq);     \
        float tt = copysignf(1.0f, tau) * __builtin_amdgcn_rcpf(             \
                     fabsf(tau) +                                            \
                     __builtin_amdgcn_sqrtf(fmaf(tau, tau, 1.0f)));          \
        tt = (apq != 0.0f) ? tt : 0.0f;                                      \
        const float c = __builtin_amdgcn_rsqf(fmaf(tt, tt, 1.0f));           \
        const float s = tt * c;                                              \
        dp -= tt * apq;                                                      \
        dq += tt * apq;                                                      \
        opq = 0.0f;                                                         \
        { const float t1 = e1p; e1p = c * t1 - s * e1q;                      \
          e1q = s * t1 + c * e1q; }                                          \
        { const float t2 = e2p; e2p = c * t2 - s * e2q;                      \
          e2q = s * t2 + c * e2q; }                                          \
        _Pragma("unroll")                                                    \
        for (int k = 0; k < 4; ++k) {                                        \
            const float a1 = Vm[k][P], a2 = Vm[k][Q];                        \
            Vm[k][P] = c * a1 - s * a2;                                      \
            Vm[k][Q] = s * a1 + c * a2;                                      \
        }                                                                    \
    }

// ---------------------------------------------------------------------------
// Fused v9: v8's quarter-wave packing + HYBRID COALESCED STAGING.
// One wave per block (BLK=64) owns 4 batches (16 lanes each).
//   - Batches g=0,1 (first 5200 floats of the wave's contiguous region) are
//     staged via global_load_lds — round-1-proven pattern, perfectly
//     coalesced 1KiB/instr, zero VGPR cost, ~21KB in flight per wave.
//     LDS reads at stride 13 dwords: <=2-way bank alias = free (m136).
//   - Batches g=2,3 load direct f4u (v8 path) — overlaps the staging drain.
//   - 20.8KB LDS/block -> 7 blocks/CU (~= v8's 8 waves/CU occupancy).
//   - Solve: branchless 4-sweep symmetric Jacobi, once per 4 batches
//     (HW-verified absmax 0.015625). Apply from registers, 12B/lane stores.
// Rationale: by elimination (VALU, chain count, barriers, HBM BW all tested
// flat/negative), the residual ~23us over the traffic floor sits in the
// divergent stride-52 load path. This converts half of it to coalesced.
// ---------------------------------------------------------------------------
__global__ __launch_bounds__(BLK, 2) void fused_kernel(
    const float* __restrict__ net_in,   // (B, 200, 13)
    const float* __restrict__ shift_p,
    const float* __restrict__ a_p,
    const float* __restrict__ b_p,
    float* __restrict__ out)            // (B, 200, 3)
{
    __shared__ float s_in[STG];           // 20,800 B -> 7 blocks/CU

    const int l = threadIdx.x;            // 0..63
    const int t = l & 15;                 // lane within quarter
    const int g = l >> 4;                 // quarter = local batch
    const int b = blockIdx.x * 4 + g;     // global batch

    const float shift = shift_p[0];
    const float aa    = a_p[0];
    const float bb    = b_p[0];

    const float* src  = net_in + (size_t)b * FPB;                  // per-lane
    const float* wsrc = net_in + (size_t)(blockIdx.x * 4) * FPB;   // uniform

    // ---- async stage batches g=0,1: 20x256 floats + 80-float tail ----
    #pragma unroll
    for (int j = 0; j < 20; ++j) {
        __builtin_amdgcn_global_load_lds(
            (const __attribute__((address_space(1))) void*)(wsrc + j * 256 + l * 4),
            (__attribute__((address_space(3))) void*)(s_in + j * 256),
            16, 0, 0);
    }
    if (l < 20) {
        __builtin_amdgcn_global_load_lds(
            (const __attribute__((address_space(1))) void*)(wsrc + 5120 + l * 4),
            (__attribute__((address_space(3))) void*)(s_in + 5120),
            16, 0, 0);
    }

    __builtin_amdgcn_s_waitcnt(0);          // drain staging
    __asm__ __volatile__("" ::: "memory");  // keep LDS reads below the wait

    // ---- per-lane accumulation; xyz2 saved in regs for the apply step ----
    float acc[16];
    #pragma unroll
    for (int k = 0; k < 16; ++k) acc[k] = 0.f;

    float sx2[13], sy2[13], sz2[13];

    if (g < 2) {
        // quarters 0,1: read from LDS (conflict-free-ish: <=2-way alias)
        const float* base = s_in + g * FPB;
        #pragma unroll
        for (int i = 0; i < 13; ++i) {
            if (i < 12 || t < 8) {
                const float* q = base + (t + 16 * i) * NCH;
                const float q0 = q[0],  q1 = q[1],  q2  = q[2],  q3  = q[3];
                const float q4 = q[4],  q5 = q[5],  q6  = q[6],  q7  = q[7];
                const float q8 = q[8],  q9 = q[9],  q10 = q[10], q11 = q[11];
                const float q12 = q[12];
                ACCUMULATE(q0, q1, q2, q3, q4, q5, q6, q7, q8, q9, q10, q11, q12)
                sx2[i] = q4; sy2[i] = q5; sz2[i] = q6;
            } else {
                sx2[i] = 0.f; sy2[i] = 0.f; sz2[i] = 0.f;
            }
        }
    } else {
        // quarters 2,3: direct f4u loads (v8-proven path)
        #pragma unroll
        for (int i = 0; i < 13; ++i) {
            if (i < 12 || t < 8) {
                const float* q = src + (t + 16 * i) * NCH;
                const f4u v0 = *(const f4u*)(q);      // w, x1,y1,z1
                const f4u v1 = *(const f4u*)(q + 4);  // x2,y2,z2, n1x
                const f4u v2 = *(const f4u*)(q + 8);  // n1y,n1z, n2x,n2y
                const float q12 = q[12];              // n2z
                ACCUMULATE(v0.x, v0.y, v0.z, v0.w,
                           v1.x, v1.y, v1.z, v1.w,
                           v2.x, v2.y, v2.z, v2.w, q12)
                sx2[i] = v1.x; sy2[i] = v1.y; sz2[i] = v1.z;
            } else {
                sx2[i] = 0.f; sy2[i] = 0.f; sz2[i] = 0.f;
            }
        }
    }

    // ---- 4-level xor-butterfly within each 16-lane quarter ----
    #pragma unroll
    for (int k = 0; k < 16; ++k) {
        acc[k] += __shfl_xor(acc[k],  8, 64);
        acc[k] += __shfl_xor(acc[k],  4, 64);
        acc[k] += __shfl_xor(acc[k],  2, 64);
        acc[k] += __shfl_xor(acc[k],  1, 64);
    }

    // ---- centroids and centered covariance S (per quarter) ----
    const float W = acc[0];
    const float invW = __builtin_amdgcn_rcpf(W);
    const float v1cx = acc[1] * invW, v1cy = acc[2] * invW, v1cz = acc[3] * invW;
    const float v2cx = acc[4] * invW, v2cy = acc[5] * invW, v2cz = acc[6] * invW;

    const float Sxx = acc[7]  - W * v2cx * v1cx;
    const float Sxy = acc[8]  - W * v2cx * v1cy;
    const float Sxz = acc[9]  - W * v2cx * v1cz;
    const float Syx = acc[10] - W * v2cy * v1cx;
    const float Syy = acc[11] - W * v2cy * v1cy;
    const float Syz = acc[12] - W * v2cy * v1cz;
    const float Szx = acc[13] - W * v2cz * v1cx;
    const float Szy = acc[14] - W * v2cz * v1cy;
    const float Szz = acc[15] - W * v2cz * v1cz;

    // ---- Horn K matrix in symmetric storage (diag d0..d3, off oPQ) ----
    float d0  = Sxx + Syy + Szz;
    float o01 = Syz - Szy;
    float o02 = Szx - Sxz;
    float o03 = Sxy - Syx;
    float d1  = Sxx - Syy - Szz;
    float o12 = Sxy + Syx;
    float o13 = Szx + Sxz;
    float d2  = -Sxx + Syy - Szz;
    float o23 = Syz + Szy;
    float d3  = -Sxx - Syy + Szz;

    float Vm[4][4] = {{1,0,0,0},{0,1,0,0},{0,0,1,0},{0,0,0,1}};

    // 4 sweeps x 6 branchless symmetric rotations (once per 4 batches)
    for (int sweep = 0; sweep < 4; ++sweep) {
        ROTB(d0, d1, o01,  o02, o12,  o03, o13,  0, 1)
        ROTB(d0, d2, o02,  o01, o12,  o03, o23,  0, 2)
        ROTB(d0, d3, o03,  o01, o13,  o02, o23,  0, 3)
        ROTB(d1, d2, o12,  o01, o02,  o13, o23,  1, 2)
        ROTB(d1, d3, o13,  o01, o03,  o12, o23,  1, 3)
        ROTB(d2, d3, o23,  o02, o03,  o12, o13,  2, 3)
    }

    // ---- best eigenvector: branchless compare chain (per-lane data) ----
    float bd = d0;
    float q0 = Vm[0][0], qx = Vm[1][0], qy = Vm[2][0], qz = Vm[3][0];
    { const bool c1 = d1 > bd;
      bd = c1 ? d1 : bd;
      q0 = c1 ? Vm[0][1] : q0; qx = c1 ? Vm[1][1] : qx;
      qy = c1 ? Vm[2][1] : qy; qz = c1 ? Vm[3][1] : qz; }
    { const bool c2 = d2 > bd;
      bd = c2 ? d2 : bd;
      q0 = c2 ? Vm[0][2] : q0; qx = c2 ? Vm[1][2] : qx;
      qy = c2 ? Vm[2][2] : qy; qz = c2 ? Vm[3][2] : qz; }
    { const bool c3 = d3 > bd;
      q0 = c3 ? Vm[0][3] : q0; qx = c3 ? Vm[1][3] : qx;
      qy = c3 ? Vm[2][3] : qy; qz = c3 ? Vm[3][3] : qz; }

    // renormalize (approx rotations leave ~1e-5 norm drift)
    const float qn = __builtin_amdgcn_rsqf(q0*q0 + qx*qx + qy*qy + qz*qz);
    q0 *= qn; qx *= qn; qy *= qn; qz *= qn;

    const float R00 = q0*q0 + qx*qx - qy*qy - qz*qz;
    const float R01 = 2.0f * (qx*qy - q0*qz);
    const float R02 = 2.0f * (qx*qz + q0*qy);
    const float R10 = 2.0f * (qx*qy + q0*qz);
    const float R11 = q0*q0 - qx*qx + qy*qy - qz*qz;
    const float R12 = 2.0f * (qy*qz - q0*qx);
    const float R20 = 2.0f * (qx*qz - q0*qy);
    const float R21 = 2.0f * (qy*qz + q0*qx);
    const float R22 = q0*q0 - qx*qx - qy*qy + qz*qz;

    const float tx = v1cx - (R00 * v2cx + R01 * v2cy + R02 * v2cz);
    const float ty = v1cy - (R10 * v2cx + R11 * v2cy + R12 * v2cz);
    const float tz = v1cz - (R20 * v2cx + R21 * v2cy + R22 * v2cz);

    // ---- apply from registers; 12B/lane stores, 192B runs per quarter ----
    float* ob = out + (size_t)b * (NPTS * 3);
    #pragma unroll
    for (int i = 0; i < 13; ++i) {
        if (i < 12 || t < 8) {
            const int p = t + 16 * i;
            const float X = sx2[i], Y = sy2[i], Z = sz2[i];
            f3s o3;
            o3.x = R00 * X + R01 * Y + R02 * Z + tx;
            o3.y = R10 * X + R11 * Y + R12 * Z + ty;
            o3.z = R20 * X + R21 * Y + R22 * Z + tz;
            *(f3s*)(ob + p * 3) = o3;
        }
    }
}

extern "C" void kernel_launch(void* const* d_in, const int* in_sizes, int n_in,
                              void* d_out, int out_size, void* d_ws, size_t ws_size,
                              hipStream_t stream) {
    const float* net_in  = (const float*)d_in[0];
    const float* shift_p = (const float*)d_in[1];
    const float* a_p     = (const float*)d_in[2];
    const float* b_p     = (const float*)d_in[3];
    float* out = (float*)d_out;

    const int B = in_sizes[0] / FPB;             // 8192
    (void)d_ws; (void)ws_size; (void)n_in; (void)out_size;

    // 4 batches per 1-wave block -> 2048 blocks
    fused_kernel<<<B / 4, BLK, 0, stream>>>(net_in, shift_p, a_p, b_p, out);
}

// Round 12
// 135.472 us; speedup vs baseline: 1.0321x; 1.0321x over previous
//
#include <hip/hip_runtime.h>
#include <math.h>

#define NPTS 200
#define NCH  13
#define BLK  256
#define FPB  (NPTS * NCH)          // 2600 floats per batch

// 4-byte-aligned float4 for dword-aligned (not 16B-aligned) vector loads
typedef float f4u __attribute__((ext_vector_type(4), aligned(4)));

// 12-byte packed store (align 4) for coalesced per-point output
typedef struct { float x, y, z; } f3s;

#define ACCUMULATE(Q0,Q1,Q2,Q3,Q4,Q5,Q6,Q7,Q8,Q9,Q10,Q11,Q12)               \
    {                                                                        \
        float wt = aa * (Q0) + bb;                                           \
        wt = fmaxf(wt, 0.f) + 1e-8f;                                         \
        const float v1x = fmaf(shift, (Q7),  (Q1));                          \
        const float v1y = fmaf(shift, (Q8),  (Q2));                          \
        const float v1z = fmaf(shift, (Q9),  (Q3));                          \
        const float v2x = fmaf(shift, (Q10), (Q4));                          \
        const float v2y = fmaf(shift, (Q11), (Q5));                          \
        const float v2z = fmaf(shift, (Q12), (Q6));                          \
        const float wv2x = wt * v2x, wv2y = wt * v2y, wv2z = wt * v2z;       \
        acc[0] += wt;                                                        \
        acc[1] += wt * v1x; acc[2] += wt * v1y; acc[3] += wt * v1z;          \
        acc[4] += wv2x;     acc[5] += wv2y;     acc[6] += wv2z;              \
        acc[7]  += wv2x * v1x; acc[8]  += wv2x * v1y; acc[9]  += wv2x * v1z; \
        acc[10] += wv2y * v1x; acc[11] += wv2y * v1y; acc[12] += wv2y * v1z; \
        acc[13] += wv2z * v1x; acc[14] += wv2z * v1y; acc[15] += wv2z * v1z; \
    }

// Branchless symmetric 4x4 Jacobi rotation on pair (P,Q) — HW-verified in
// v6/v7/v8 at absmax 0.015625. apq==0 => identity rotation; NaN killed by
// the select.
#define ROTB(dp, dq, opq, e1p, e1q, e2p, e2q, P, Q)                          \
    {                                                                        \
        const float apq = opq;                                               \
        const float tau = (dq - dp) * 0.5f * __builtin_amdgcn_rcpf(apq);     \
        float tt = copysignf(1.0f, tau) * __builtin_amdgcn_rcpf(             \
                     fabsf(tau) +                                            \
                     __builtin_amdgcn_sqrtf(fmaf(tau, tau, 1.0f)));          \
        tt = (apq != 0.0f) ? tt : 0.0f;                                      \
        const float c = __builtin_amdgcn_rsqf(fmaf(tt, tt, 1.0f));           \
        const float s = tt * c;                                              \
        dp -= tt * apq;                                                      \
        dq += tt * apq;                                                      \
        opq = 0.0f;                                                         \
        { const float t1 = e1p; e1p = c * t1 - s * e1q;                      \
          e1q = s * t1 + c * e1q; }                                          \
        { const float t2 = e2p; e2p = c * t2 - s * e2q;                      \
          e2q = s * t2 + c * e2q; }                                          \
        _Pragma("unroll")                                                    \
        for (int k = 0; k < 4; ++k) {                                        \
            const float a1 = Vm[k][P], a2 = Vm[k][Q];                        \
            Vm[k][P] = c * a1 - s * a2;                                      \
            Vm[k][Q] = s * a1 + c * a2;                                      \
        }                                                                    \
    }

// ---------------------------------------------------------------------------
// Fused v10: v8's quarter-wave packing + EXPLICIT ALL-LOADS-FIRST PIPELINE.
// Elimination table after 9 measured variants: VALU issue, solve-chain
// count, barriers, HBM BW, TA-coalescing (x2) — all flat/negative. The
// untested mechanism is per-wave MLP: v4's VGPR_Count=44 proves the
// compiler's pressure heuristic serialized the 52-load stream into ~13
// dependent latency exposures. v8's grid (512 blocks) limits occupancy to
// 2 blocks/CU anyway, so a 256-VGPR budget is FREE:
//   - phase A: issue all 52 loads back-to-back into named register arrays
//     (compile-time indices only); 52 in flight/wave x 8 waves/CU ~= 416
//     outstanding requests/CU (~20x today's MLP), under the 63-vmcnt cap
//   - phase B: accumulate from registers; L1[] (xyz2) persists to apply
//   - solve: branchless 4-sweep symmetric Jacobi once per 4 batches
//     (HW-verified absmax 0.015625); apply from regs, 12B/lane stores
// Zero LDS, zero barriers, zero cross-wave communication.
// ---------------------------------------------------------------------------
__global__ __launch_bounds__(BLK, 2) void fused_kernel(
    const float* __restrict__ net_in,   // (B, 200, 13)
    const float* __restrict__ shift_p,
    const float* __restrict__ a_p,
    const float* __restrict__ b_p,
    float* __restrict__ out)            // (B, 200, 3)
{
    const int tid = threadIdx.x;
    const int w   = tid >> 6;             // wave id in block
    const int l   = tid & 63;
    const int t   = l & 15;               // lane within quarter
    const int b   = (blockIdx.x * 4 + w) * 4 + (l >> 4);  // per-quarter batch

    const float shift = shift_p[0];
    const float aa    = a_p[0];
    const float bb    = b_p[0];

    const float* src = net_in + (size_t)b * FPB;

    // ---- phase A: issue ALL 52 loads back-to-back (max MLP) ----
    f4u  L0[13], L1[13], L2[13];
    float L3[13];
    #pragma unroll
    for (int i = 0; i < 13; ++i) {
        if (i < 12 || t < 8) {            // i<12 always valid; i==12 only t<8
            const float* q = src + (t + 16 * i) * NCH;
            L0[i] = *(const f4u*)(q);      // w, x1,y1,z1
            L1[i] = *(const f4u*)(q + 4);  // x2,y2,z2, n1x
            L2[i] = *(const f4u*)(q + 8);  // n1y,n1z, n2x,n2y
            L3[i] = q[12];                 // n2z
        } else {
            L0[i] = (f4u){0.f,0.f,0.f,0.f};
            L1[i] = (f4u){0.f,0.f,0.f,0.f};
            L2[i] = (f4u){0.f,0.f,0.f,0.f};
            L3[i] = 0.f;
        }
    }

    // ---- phase B: accumulate from registers ----
    float acc[16];
    #pragma unroll
    for (int k = 0; k < 16; ++k) acc[k] = 0.f;

    #pragma unroll
    for (int i = 0; i < 13; ++i) {
        if (i < 12 || t < 8) {
            ACCUMULATE(L0[i].x, L0[i].y, L0[i].z, L0[i].w,
                       L1[i].x, L1[i].y, L1[i].z, L1[i].w,
                       L2[i].x, L2[i].y, L2[i].z, L2[i].w, L3[i])
        }
    }

    // ---- 4-level xor-butterfly within each 16-lane quarter ----
    #pragma unroll
    for (int k = 0; k < 16; ++k) {
        acc[k] += __shfl_xor(acc[k],  8, 64);
        acc[k] += __shfl_xor(acc[k],  4, 64);
        acc[k] += __shfl_xor(acc[k],  2, 64);
        acc[k] += __shfl_xor(acc[k],  1, 64);
    }

    // ---- centroids and centered covariance S (per quarter) ----
    const float W = acc[0];
    const float invW = __builtin_amdgcn_rcpf(W);
    const float v1cx = acc[1] * invW, v1cy = acc[2] * invW, v1cz = acc[3] * invW;
    const float v2cx = acc[4] * invW, v2cy = acc[5] * invW, v2cz = acc[6] * invW;

    const float Sxx = acc[7]  - W * v2cx * v1cx;
    const float Sxy = acc[8]  - W * v2cx * v1cy;
    const float Sxz = acc[9]  - W * v2cx * v1cz;
    const float Syx = acc[10] - W * v2cy * v1cx;
    const float Syy = acc[11] - W * v2cy * v1cy;
    const float Syz = acc[12] - W * v2cy * v1cz;
    const float Szx = acc[13] - W * v2cz * v1cx;
    const float Szy = acc[14] - W * v2cz * v1cy;
    const float Szz = acc[15] - W * v2cz * v1cz;

    // ---- Horn K matrix in symmetric storage (diag d0..d3, off oPQ) ----
    float d0  = Sxx + Syy + Szz;
    float o01 = Syz - Szy;
    float o02 = Szx - Sxz;
    float o03 = Sxy - Syx;
    float d1  = Sxx - Syy - Szz;
    float o12 = Sxy + Syx;
    float o13 = Szx + Sxz;
    float d2  = -Sxx + Syy - Szz;
    float o23 = Syz + Szy;
    float d3  = -Sxx - Syy + Szz;

    float Vm[4][4] = {{1,0,0,0},{0,1,0,0},{0,0,1,0},{0,0,0,1}};

    // 4 sweeps x 6 branchless symmetric rotations (once per 4 batches)
    for (int sweep = 0; sweep < 4; ++sweep) {
        ROTB(d0, d1, o01,  o02, o12,  o03, o13,  0, 1)
        ROTB(d0, d2, o02,  o01, o12,  o03, o23,  0, 2)
        ROTB(d0, d3, o03,  o01, o13,  o02, o23,  0, 3)
        ROTB(d1, d2, o12,  o01, o02,  o13, o23,  1, 2)
        ROTB(d1, d3, o13,  o01, o03,  o12, o23,  1, 3)
        ROTB(d2, d3, o23,  o02, o03,  o12, o13,  2, 3)
    }

    // ---- best eigenvector: branchless compare chain (per-lane data) ----
    float bd = d0;
    float q0 = Vm[0][0], qx = Vm[1][0], qy = Vm[2][0], qz = Vm[3][0];
    { const bool c1 = d1 > bd;
      bd = c1 ? d1 : bd;
      q0 = c1 ? Vm[0][1] : q0; qx = c1 ? Vm[1][1] : qx;
      qy = c1 ? Vm[2][1] : qy; qz = c1 ? Vm[3][1] : qz; }
    { const bool c2 = d2 > bd;
      bd = c2 ? d2 : bd;
      q0 = c2 ? Vm[0][2] : q0; qx = c2 ? Vm[1][2] : qx;
      qy = c2 ? Vm[2][2] : qy; qz = c2 ? Vm[3][2] : qz; }
    { const bool c3 = d3 > bd;
      q0 = c3 ? Vm[0][3] : q0; qx = c3 ? Vm[1][3] : qx;
      qy = c3 ? Vm[2][3] : qy; qz = c3 ? Vm[3][3] : qz; }

    // renormalize (approx rotations leave ~1e-5 norm drift)
    const float qn = __builtin_amdgcn_rsqf(q0*q0 + qx*qx + qy*qy + qz*qz);
    q0 *= qn; qx *= qn; qy *= qn; qz *= qn;

    const float R00 = q0*q0 + qx*qx - qy*qy - qz*qz;
    const float R01 = 2.0f * (qx*qy - q0*qz);
    const float R02 = 2.0f * (qx*qz + q0*qy);
    const float R10 = 2.0f * (qx*qy + q0*qz);
    const float R11 = q0*q0 - qx*qx + qy*qy - qz*qz;
    const float R12 = 2.0f * (qy*qz - q0*qx);
    const float R20 = 2.0f * (qx*qz - q0*qy);
    const float R21 = 2.0f * (qy*qz + q0*qx);
    const float R22 = q0*q0 - qx*qx - qy*qy + qz*qz;

    const float tx = v1cx - (R00 * v2cx + R01 * v2cy + R02 * v2cz);
    const float ty = v1cy - (R10 * v2cx + R11 * v2cy + R12 * v2cz);
    const float tz = v1cz - (R20 * v2cx + R21 * v2cy + R22 * v2cz);

    // ---- apply: xyz2 comes straight from the persisted L1[] registers ----
    float* ob = out + (size_t)b * (NPTS * 3);
    #pragma unroll
    for (int i = 0; i < 13; ++i) {
        if (i < 12 || t < 8) {
            const int p = t + 16 * i;
            const float X = L1[i].x, Y = L1[i].y, Z = L1[i].z;
            f3s o3;
            o3.x = R00 * X + R01 * Y + R02 * Z + tx;
            o3.y = R10 * X + R11 * Y + R12 * Z + ty;
            o3.z = R20 * X + R21 * Y + R22 * Z + tz;
            *(f3s*)(ob + p * 3) = o3;
        }
    }
}

extern "C" void kernel_launch(void* const* d_in, const int* in_sizes, int n_in,
                              void* d_out, int out_size, void* d_ws, size_t ws_size,
                              hipStream_t stream) {
    const float* net_in  = (const float*)d_in[0];
    const float* shift_p = (const float*)d_in[1];
    const float* a_p     = (const float*)d_in[2];
    const float* b_p     = (const float*)d_in[3];
    float* out = (float*)d_out;

    const int B = in_sizes[0] / FPB;             // 8192
    (void)d_ws; (void)ws_size; (void)n_in; (void)out_size;

    // 16 batches per block (4 waves x 4 quarter-wave batches) -> 512 blocks
    fused_kernel<<<B / 16, BLK, 0, stream>>>(net_in, shift_p, a_p, b_p, out);
}